// Round 8
// baseline (303.979 us; speedup 1.0000x reference)
//
#include <hip/hip_runtime.h>
#include <hip/hip_fp16.h>

#define NBMAX 256   // coarse buckets (N/512), must be <= 256
#define BCAP  8192  // fixed edge capacity per bucket (mean 6144, +26 sigma)
#define CHB   3584  // edges per binning block (335 blocks -> fills 256 CUs)

typedef _Float16 half8 __attribute__((ext_vector_type(8)));
typedef float f32x4 __attribute__((ext_vector_type(4)));

__device__ __forceinline__ unsigned short f2h(float f) {
    __half h = __float2half_rn(f);
    return *(unsigned short*)&h;
}

// exclusive scan of v over 256 threads (4 waves); all threads must call
__device__ __forceinline__ int scan256(int v, int* wsum, int* woff) {
    int t = threadIdx.x, lane = t & 63, wv = t >> 6;
    int x = v;
    #pragma unroll
    for (int d = 1; d < 64; d <<= 1) {
        int y = __shfl_up(x, d, 64);
        if (lane >= d) x += y;
    }
    if (lane == 63) wsum[wv] = x;
    __syncthreads();
    if (t == 0) {
        int a = 0;
        #pragma unroll
        for (int i = 0; i < 4; ++i) { woff[i] = a; a += wsum[i]; }
    }
    __syncthreads();
    return x - v + woff[wv];
}

// ---------------- combined prep: binscatter (blocks < nbin) ∥ x->fp16 ---------
__global__ __launch_bounds__(256) void gin_prep(const float* __restrict__ x,
                                                unsigned short* __restrict__ o, int n16,
                                                const void* __restrict__ edge,
                                                int* __restrict__ gcount,
                                                uint2* __restrict__ ebuf,
                                                int E, int nb, int nbin) {
    if ((int)blockIdx.x >= nbin) {
        // ---- x16 role ----
        int i = (blockIdx.x - nbin) * 256 + threadIdx.x;  // one float4 group
        if (i >= n16) return;
        float4 v = ((const float4*)x)[i];
        ushort4 u;
        u.x = f2h(v.x); u.y = f2h(v.y); u.z = f2h(v.z); u.w = f2h(v.w);
        ((ushort4*)o)[i] = u;
        return;
    }
    // ---- binscatter role ----
    __shared__ int cnt[NBMAX];
    __shared__ int dlt[NBMAX];
    __shared__ int cur[NBMAX];
    __shared__ int wsum[4], woff[4];
    __shared__ int s_is64;
    __shared__ uint2 buf[CHB];
    int t = threadIdx.x;
    int beg = blockIdx.x * CHB;
    int m = E - beg; if (m > CHB) m = CHB;
    if (t < nb) cnt[t] = 0;
    if (t == 0) s_is64 = 1;
    __syncthreads();
    {   // dtype detect: int64 edges have zero high words (ids << 2^32)
        int m2 = (E < 64) ? E : 64;
        if (t < m2 && ((const int*)edge)[2 * t + 1] != 0) s_is64 = 0;  // benign race
    }
    __syncthreads();
    int is64 = s_is64;
    for (int j = t; j < m; j += 256) {
        int e = beg + j;
        int d = is64 ? (int)((const long long*)edge)[E + e] : ((const int*)edge)[E + e];
        atomicAdd(&cnt[d >> 9], 1);
    }
    __syncthreads();
    int v = (t < nb) ? cnt[t] : 0;
    int excl = scan256(v, wsum, woff);
    if (t < nb) {
        int gb = v ? atomicAdd(&gcount[t], v) : 0;
        dlt[t] = t * BCAP + gb - excl;
        cur[t] = excl;
    }
    __syncthreads();
    for (int j = t; j < m; j += 256) {
        int e = beg + j;
        int s, d;
        if (is64) {
            s = (int)((const long long*)edge)[e];
            d = (int)((const long long*)edge)[E + e];
        } else {
            s = ((const int*)edge)[e];
            d = ((const int*)edge)[E + e];
        }
        int p = atomicAdd(&cur[d >> 9], 1);
        buf[p] = make_uint2((unsigned)s, (unsigned)d);
    }
    __syncthreads();
    for (int j = t; j < m; j += 256) {
        uint2 ed = buf[j];
        ebuf[j + dlt[(int)(ed.y >> 9)]] = ed;  // contiguous runs per bucket
    }
}

// ---------------- per-bucket CSR build (512 nodes/block) ----------------
__global__ __launch_bounds__(256) void gin_build(const uint2* __restrict__ ebuf,
                                                 const int* __restrict__ gcount,
                                                 int* __restrict__ rowbeg,
                                                 int* __restrict__ rowend,
                                                 int* __restrict__ col, int n) {
    __shared__ int cnt[512];
    __shared__ int off[512];
    __shared__ int wsum[4], woff[4];
    int b = blockIdx.x, t = threadIdx.x;
    int beg = b * BCAP;
    int end = beg + gcount[b];
    cnt[t] = 0; cnt[t + 256] = 0;
    __syncthreads();
    for (int j = beg + t; j < end; j += 256)
        atomicAdd(&cnt[(int)(ebuf[j].y & 511)], 1);
    __syncthreads();
    int v0 = cnt[2 * t], v1 = cnt[2 * t + 1];
    int ep = scan256(v0 + v1, wsum, woff);
    off[2 * t] = ep;
    off[2 * t + 1] = ep + v0;
    __syncthreads();
    int node0 = b * 512 + 2 * t;
    if (node0 < n) {
        rowbeg[node0] = beg + off[2 * t];
        rowend[node0] = beg + off[2 * t] + v0;
    }
    if (node0 + 1 < n) {
        rowbeg[node0 + 1] = beg + off[2 * t + 1];
        rowend[node0 + 1] = beg + off[2 * t + 1] + v1;
    }
    __syncthreads();
    for (int j = beg + t; j < end; j += 256) {
        uint2 ed = ebuf[j];
        int p = atomicAdd(&off[(int)(ed.y & 511)], 1);
        col[beg + p] = (int)ed.x;
    }
}

// ---------------- gather core (fp16 rows, 4 nodes per wave) ----------
template <bool APPLY>
__device__ __forceinline__ void accum8(float* acc, uint4 u,
                                       const float* sc, const float* sh) {
    float v[8];
    float2 f;
    f = __half22float2(*(const __half2*)&u.x); v[0] = f.x; v[1] = f.y;
    f = __half22float2(*(const __half2*)&u.y); v[2] = f.x; v[3] = f.y;
    f = __half22float2(*(const __half2*)&u.z); v[4] = f.x; v[5] = f.y;
    f = __half22float2(*(const __half2*)&u.w); v[6] = f.x; v[7] = f.y;
    #pragma unroll
    for (int j = 0; j < 8; ++j)
        acc[j] += APPLY ? fmaxf(fmaf(v[j], sc[j], sh[j]), 0.f) : v[j];
}

// writes the node's 64-feature t-row (fp16) to trow (LDS), stride-free.
// ci0 = prefetched col indices for the FIRST 16-edge chunk (issued a pass ago)
template <bool APPLY>
__device__ __forceinline__ void gather_node(const unsigned short* __restrict__ zb,
                                            int r0, int r1, int ci0,
                                            const int* __restrict__ col,
                                            float e1,
                                            const float* sc, const float* sh,
                                            _Float16* __restrict__ trow,
                                            int wid, int qn, int l16) {
    int r = l16 >> 3, c = l16 & 7;  // row parity / feature chunk (8 features)
    // self row (only r==0 lanes consume; issued early so it's in flight)
    uint4 su = make_uint4(0, 0, 0, 0);
    if (r == 0) su = *(const uint4*)(zb + (size_t)wid * 64 + 8 * c);

    float acc[8] = {0.f, 0.f, 0.f, 0.f, 0.f, 0.f, 0.f, 0.f};
    int ci = ci0;
    for (int b2 = r0; b2 < r1; b2 += 16) {
        if (b2 > r0) {  // chunk 0 uses the prefetched ci0
            int ce = b2 + l16;
            ci = col[ce < r1 ? ce : r1 - 1];  // 1 load -> 16 neighbor indices
        }
        uint4 u[8];
        bool p[8];
        #pragma unroll
        for (int s = 0; s < 8; ++s) {
            int j = 2 * s + r;
            p[s] = (b2 + j) < r1;
            int idx = __shfl(ci, 16 * qn + j);
            if (p[s]) u[s] = *(const uint4*)(zb + (size_t)idx * 64 + 8 * c);
        }
        #pragma unroll
        for (int s = 0; s < 8; ++s)
            if (p[s]) accum8<APPLY>(acc, u[s], sc, sh);
    }
    // reduce the 2 row parities — xor 8 stays inside this 16-lane quarter
    #pragma unroll
    for (int j = 0; j < 8; ++j)
        acc[j] += __shfl_xor(acc[j], 8);
    if (r == 0) {
        float s[8];
        float2 f;
        f = __half22float2(*(const __half2*)&su.x); s[0] = f.x; s[1] = f.y;
        f = __half22float2(*(const __half2*)&su.y); s[2] = f.x; s[3] = f.y;
        f = __half22float2(*(const __half2*)&su.z); s[4] = f.x; s[5] = f.y;
        f = __half22float2(*(const __half2*)&su.w); s[6] = f.x; s[7] = f.y;
        #pragma unroll
        for (int j = 0; j < 8; ++j) {
            float v = APPLY ? fmaxf(fmaf(s[j], sc[j], sh[j]), 0.f) : s[j];
            acc[j] = fmaf(e1, v, acc[j]);
        }
        uint4 o;
        o.x = (unsigned)f2h(acc[0]) | ((unsigned)f2h(acc[1]) << 16);
        o.y = (unsigned)f2h(acc[2]) | ((unsigned)f2h(acc[3]) << 16);
        o.z = (unsigned)f2h(acc[4]) | ((unsigned)f2h(acc[5]) << 16);
        o.w = (unsigned)f2h(acc[6]) | ((unsigned)f2h(acc[7]) << 16);
        *(uint4*)(trow + 8 * c) = o;
    }
}

// ---------------- one GIN layer for a 128-node block (shared by fused/mega) ---
// caller must have staged Wt (both mms), zeroed sS/sQ, computed sBN (if APPLY),
// and issued a __syncthreads(). Ends with stats flushed (block-synced).
template <bool APPLY>
__device__ __forceinline__ void gin_layer(const unsigned short* __restrict__ zb,
                                          const int* __restrict__ rowbeg,
                                          const int* __restrict__ rowend,
                                          const int* __restrict__ col,
                                          float e1,
                                          const float* __restrict__ b1,
                                          const float* __restrict__ b2,
                                          float* __restrict__ statsL,
                                          _Float16* __restrict__ Wt,
                                          _Float16* __restrict__ Tz,
                                          float* __restrict__ sS,
                                          float* __restrict__ sQ,
                                          const float* __restrict__ sBN,
                                          int base, int n) {
    int tid = threadIdx.x;
    int lane = tid & 63, wv = tid >> 6;   // wv 0..7
    int qn = lane >> 4;
    int l16 = lane & 15;
    int c8 = l16 & 7;
    float sc[8] = {1.f, 1.f, 1.f, 1.f, 1.f, 1.f, 1.f, 1.f};
    float sh[8] = {0.f, 0.f, 0.f, 0.f, 0.f, 0.f, 0.f, 0.f};
    if (APPLY) {
        *(float4*)&sc[0] = *(const float4*)&sBN[8 * c8];
        *(float4*)&sc[4] = *(const float4*)&sBN[8 * c8 + 4];
        *(float4*)&sh[0] = *(const float4*)&sBN[64 + 8 * c8];
        *(float4*)&sh[4] = *(const float4*)&sBN[64 + 8 * c8 + 4];
    }

    // ---- phase 1: gather 128 t-rows into Tz (4 passes of 32 nodes) ----
    int wvq = wv * 4 + qn;   // 0..31
    int cr0, cr1, pr0, pr1;
    {   // extents for pass 0 and 1
        int w0 = base + wvq;
        cr0 = 0; cr1 = 0;
        if (w0 < n) { cr0 = rowbeg[w0]; cr1 = rowend[w0]; }
        int w1 = w0 + 32;
        pr0 = 0; pr1 = 0;
        if (w1 < n) { pr0 = rowbeg[w1]; pr1 = rowend[w1]; }
    }
    int cci = 0;
    if (cr1 > cr0) { int ce = cr0 + l16; cci = col[ce < cr1 ? ce : cr1 - 1]; }
    #pragma unroll 1
    for (int p = 0; p < 4; ++p) {
        int nci = 0;
        if (pr1 > pr0) { int ce = pr0 + l16; nci = col[ce < pr1 ? ce : pr1 - 1]; }
        int fr0 = 0, fr1 = 0;
        {
            int w2 = base + (p + 2) * 32 + wvq;
            if (p < 2 && w2 < n) { fr0 = rowbeg[w2]; fr1 = rowend[w2]; }
        }
        int widl = p * 32 + wvq;
        int wid = base + widl;
        if (wid < n) {
            gather_node<APPLY>(zb, cr0, cr1, cci, col, e1, sc, sh,
                               Tz + widl * 72, wid, qn, l16);
        } else if (l16 < 8) {
            *(uint4*)(Tz + widl * 72 + 8 * c8) = make_uint4(0u, 0u, 0u, 0u);
        }
        cr0 = pr0; cr1 = pr1; cci = nci;
        pr0 = fr0; pr1 = fr1;
    }
    __syncthreads();

    // ---- phase 2: MFMA MLP, one 16-row tile per wave ----
    int g = qn, q = l16;
    int n0 = 16 * wv + q;        // node row (block-local)

    half8 tb0 = *(const half8*)&Tz[n0 * 72 + 8 * g];
    half8 tb1 = *(const half8*)&Tz[n0 * 72 + 32 + 8 * g];

    f32x4 acc[4];
    #pragma unroll
    for (int ft = 0; ft < 4; ++ft)
        acc[ft] = (f32x4){0.f, 0.f, 0.f, 0.f};

    // ---- mm1 ----
    #pragma unroll
    for (int ft = 0; ft < 4; ++ft) {
        half8 a0 = *(const half8*)&Wt[(16 * ft + q) * 72 + 8 * g];
        half8 a1 = *(const half8*)&Wt[(16 * ft + q) * 72 + 32 + 8 * g];
        acc[ft] = __builtin_amdgcn_mfma_f32_16x16x32_f16(a0, tb0, acc[ft], 0, 0, 0);
        acc[ft] = __builtin_amdgcn_mfma_f32_16x16x32_f16(a1, tb1, acc[ft], 0, 0, 0);
    }

    // ---- epilogue 1: bias + relu -> Tz reused as Z1 (own rows, no barrier) ----
    #pragma unroll
    for (int ft = 0; ft < 4; ++ft) {
        float4 b = *(const float4*)(b1 + 16 * ft + 4 * g);
        float v0 = fmaxf(acc[ft][0] + b.x, 0.f);
        float v1 = fmaxf(acc[ft][1] + b.y, 0.f);
        float v2 = fmaxf(acc[ft][2] + b.z, 0.f);
        float v3 = fmaxf(acc[ft][3] + b.w, 0.f);
        uint2 pk;
        pk.x = (unsigned)f2h(v0) | ((unsigned)f2h(v1) << 16);
        pk.y = (unsigned)f2h(v2) | ((unsigned)f2h(v3) << 16);
        *(uint2*)&Tz[n0 * 72 + 16 * ft + 4 * g] = pk;
    }

    // ---- mm2 (reads back own rows; lockstep intra-wave ordering) ----
    half8 zb0 = *(const half8*)&Tz[n0 * 72 + 8 * g];
    half8 zb1 = *(const half8*)&Tz[n0 * 72 + 32 + 8 * g];
    #pragma unroll
    for (int ft = 0; ft < 4; ++ft)
        acc[ft] = (f32x4){0.f, 0.f, 0.f, 0.f};
    #pragma unroll
    for (int ft = 0; ft < 4; ++ft) {
        half8 a0 = *(const half8*)&Wt[4608 + (16 * ft + q) * 72 + 8 * g];
        half8 a1 = *(const half8*)&Wt[4608 + (16 * ft + q) * 72 + 32 + 8 * g];
        acc[ft] = __builtin_amdgcn_mfma_f32_16x16x32_f16(a0, zb0, acc[ft], 0, 0, 0);
        acc[ft] = __builtin_amdgcn_mfma_f32_16x16x32_f16(a1, zb1, acc[ft], 0, 0, 0);
    }

    // ---- epilogue 2: bias + relu, BN stats, pack into Tz (own rows) ----
    int nodeg = base + n0;
    #pragma unroll
    for (int ft = 0; ft < 4; ++ft) {
        float4 b = *(const float4*)(b2 + 16 * ft + 4 * g);
        float v0 = fmaxf(acc[ft][0] + b.x, 0.f);
        float v1 = fmaxf(acc[ft][1] + b.y, 0.f);
        float v2 = fmaxf(acc[ft][2] + b.z, 0.f);
        float v3 = fmaxf(acc[ft][3] + b.w, 0.f);
        float s[4], sq[4];
        bool ok = nodeg < n;
        s[0] = ok ? v0 : 0.f; sq[0] = ok ? v0 * v0 : 0.f;
        s[1] = ok ? v1 : 0.f; sq[1] = ok ? v1 * v1 : 0.f;
        s[2] = ok ? v2 : 0.f; sq[2] = ok ? v2 * v2 : 0.f;
        s[3] = ok ? v3 : 0.f; sq[3] = ok ? v3 * v3 : 0.f;
        uint2 pk;
        pk.x = (unsigned)f2h(v0) | ((unsigned)f2h(v1) << 16);
        pk.y = (unsigned)f2h(v2) | ((unsigned)f2h(v3) << 16);
        *(uint2*)&Tz[n0 * 72 + 16 * ft + 4 * g] = pk;
        #pragma unroll
        for (int off = 1; off < 16; off <<= 1) {
            #pragma unroll
            for (int r2 = 0; r2 < 4; ++r2) {
                s[r2] += __shfl_xor(s[r2], off);
                sq[r2] += __shfl_xor(sq[r2], off);
            }
        }
        if (q == 0) {
            #pragma unroll
            for (int r2 = 0; r2 < 4; ++r2) {
                atomicAdd(&sS[16 * ft + 4 * g + r2], s[r2]);
                atomicAdd(&sQ[16 * ft + 4 * g + r2], sq[r2]);
            }
        }
    }
    __syncthreads();
    if (tid < 64) {
        atomicAdd(&statsL[tid], sS[tid]);
        atomicAdd(&statsL[64 + tid], sQ[tid]);
    }
}

// coalesced z16 copy-out: wave writes its own 16 rows (2 KB)
__device__ __forceinline__ void copyout_z16(const _Float16* __restrict__ Tz,
                                            unsigned short* __restrict__ z16,
                                            int base, int n) {
    int lane = threadIdx.x & 63, wv = threadIdx.x >> 6;
    #pragma unroll
    for (int t2 = 0; t2 < 2; ++t2) {
        int u = lane + 64 * t2;              // uint4 index within wave region
        int rloc = 16 * wv + (u >> 3);
        int node = base + rloc;
        if (node < n) {
            uint4 v = *(const uint4*)&Tz[rloc * 72 + (u & 7) * 8];
            *(uint4*)(z16 + (size_t)node * 64 + (u & 7) * 8) = v;
        }
    }
}

// ---------------- fallback per-layer kernel (round-6 proven) ------------------
template <bool APPLY>
__global__ __launch_bounds__(512, 4) void gin_fused(const unsigned short* __restrict__ zb,
                                                    const int* __restrict__ rowbeg,
                                                    const int* __restrict__ rowend,
                                                    const int* __restrict__ col,
                                                    const float* __restrict__ epss,
                                                    const float* __restrict__ gammas,
                                                    const float* __restrict__ betas,
                                                    float fN,
                                                    unsigned short* __restrict__ z16,
                                                    const float* __restrict__ W1g,
                                                    const float* __restrict__ b1g,
                                                    const float* __restrict__ W2g,
                                                    const float* __restrict__ b2g,
                                                    float* __restrict__ stats,
                                                    int layer, int n) {
    __shared__ _Float16 Wt[2 * 64 * 72];
    __shared__ _Float16 Tz[128 * 72];
    __shared__ float sS[64], sQ[64];
    __shared__ float sBN[128];
    int tid = threadIdx.x;
    int base = blockIdx.x * 128;
    const float* __restrict__ W1 = W1g + layer * 4096;
    const float* __restrict__ W2 = W2g + layer * 4096;
    for (int i = tid; i < 4096; i += 512) {
        int k = i >> 6, nn = i & 63;
        Wt[nn * 72 + k]        = (_Float16)W1[i];
        Wt[4608 + nn * 72 + k] = (_Float16)W2[i];
    }
    if (tid < 64) {
        sS[tid] = 0.f; sQ[tid] = 0.f;
        if (APPLY) {
            float mu  = stats[(layer - 1) * 128 + tid] / fN;
            float var = stats[(layer - 1) * 128 + 64 + tid] / fN - mu * mu;
            float g   = gammas[(layer - 1) * 64 + tid];
            float grs = g * rsqrtf(var + 1e-5f);
            sBN[tid]      = grs;
            sBN[64 + tid] = betas[(layer - 1) * 64 + tid] - grs * mu;
        }
    }
    __syncthreads();
    gin_layer<APPLY>(zb, rowbeg, rowend, col, 1.f + epss[layer],
                     b1g + layer * 64, b2g + layer * 64, stats + layer * 128,
                     Wt, Tz, sS, sQ, sBN, base, n);
    copyout_z16(Tz, z16, base, n);
}

// ---------------- device-wide barrier (all blocks resident, gated on host) ----
__device__ __forceinline__ void megabar(int* __restrict__ bar, int target) {
    __syncthreads();
    if (threadIdx.x == 0) {
        __threadfence();   // release: drain + L2 writeback (device scope)
        __hip_atomic_fetch_add(bar, 1, __ATOMIC_RELEASE, __HIP_MEMORY_SCOPE_AGENT);
        while (__hip_atomic_load(bar, __ATOMIC_ACQUIRE, __HIP_MEMORY_SCOPE_AGENT) < target)
            __builtin_amdgcn_s_sleep(16);
    }
    __syncthreads();
    __threadfence();       // acquire: invalidate local caches before cross-XCD reads
}

// ---------------- persistent megakernel: 3 layers + final linear --------------
// Launched only when all blocks are co-resident (host occupancy gate).
// launch_bounds(512,8): VGPR<=64 so registers can never cut residency below
// the LDS-set 4 blocks/CU (37.9KB -> 4/CU -> 1024 slots >= grid).
__global__ __launch_bounds__(512, 8) void gin_mega(const unsigned short* __restrict__ x16,
                                                   unsigned short* __restrict__ hA,
                                                   unsigned short* __restrict__ hB,
                                                   const int* __restrict__ rowbeg,
                                                   const int* __restrict__ rowend,
                                                   const int* __restrict__ col,
                                                   const float* __restrict__ epss,
                                                   const float* __restrict__ gammas,
                                                   const float* __restrict__ betas,
                                                   float fN,
                                                   const float* __restrict__ W1g,
                                                   const float* __restrict__ b1g,
                                                   const float* __restrict__ W2g,
                                                   const float* __restrict__ b2g,
                                                   float* __restrict__ stats, int n,
                                                   const float* __restrict__ lw,
                                                   const float* __restrict__ lb,
                                                   float* __restrict__ out,
                                                   int* __restrict__ bar, int nblocks) {
    __shared__ _Float16 Wt[2 * 64 * 72];
    __shared__ _Float16 Tz[128 * 72];
    __shared__ float sS[64], sQ[64];
    __shared__ float sBN[128];
    int tid = threadIdx.x;
    int base = blockIdx.x * 128;

    #pragma unroll 1
    for (int L = 0; L < 3; ++L) {
        const unsigned short* zb = (L == 0) ? x16 : ((L == 1) ? hA : hB);
        const float* W1 = W1g + L * 4096;
        const float* W2 = W2g + L * 4096;
        for (int i = tid; i < 4096; i += 512) {
            int k = i >> 6, nn = i & 63;
            Wt[nn * 72 + k]        = (_Float16)W1[i];
            Wt[4608 + nn * 72 + k] = (_Float16)W2[i];
        }
        if (tid < 64) {
            sS[tid] = 0.f; sQ[tid] = 0.f;
            if (L > 0) {   // stats[L-1] fresh: read after previous megabar
                float mu  = stats[(L - 1) * 128 + tid] / fN;
                float var = stats[(L - 1) * 128 + 64 + tid] / fN - mu * mu;
                float g   = gammas[(L - 1) * 64 + tid];
                float grs = g * rsqrtf(var + 1e-5f);
                sBN[tid]      = grs;
                sBN[64 + tid] = betas[(L - 1) * 64 + tid] - grs * mu;
            }
        }
        __syncthreads();
        float e1 = 1.f + epss[L];
        if (L > 0)
            gin_layer<true>(zb, rowbeg, rowend, col, e1, b1g + L * 64, b2g + L * 64,
                            stats + L * 128, Wt, Tz, sS, sQ, sBN, base, n);
        else
            gin_layer<false>(zb, rowbeg, rowend, col, e1, b1g, b2g,
                             stats, Wt, Tz, sS, sQ, sBN, base, n);
        if (L < 2) copyout_z16(Tz, (L == 0) ? hA : hB, base, n);
        megabar(bar, nblocks * (L + 1));
    }

    // ---- final linear from resident Tz (layer-2 rows), BN folded ----
    float* Wl = (float*)Wt;                   // Wt dead -> 8 KB fp32 [64][32]
    for (int i = tid; i < 2048; i += 512) Wl[i] = lw[i];
    if (tid < 64) {
        float mu  = stats[256 + tid] / fN;
        float var = stats[256 + 64 + tid] / fN - mu * mu;
        float g2  = gammas[128 + tid];
        float grs = g2 * rsqrtf(var + 1e-5f);
        sBN[tid]      = grs;
        sBN[64 + tid] = betas[128 + tid] - grs * mu;
    }
    __syncthreads();
    int tx = tid & 7, ty = tid >> 3;          // 8 x 64
    float accL[2][4];
    {
        float4 b = *(const float4*)(lb + 4 * tx);
        #pragma unroll
        for (int r = 0; r < 2; ++r) {
            accL[r][0] = b.x; accL[r][1] = b.y; accL[r][2] = b.z; accL[r][3] = b.w;
        }
    }
    #pragma unroll 4
    for (int k = 0; k < 64; ++k) {
        float4 w2 = *(const float4*)&Wl[k * 32 + 4 * tx];
        float s_ = sBN[k], h_ = sBN[64 + k];
        #pragma unroll
        for (int r = 0; r < 2; ++r) {
            int row = ty + 64 * r;
            float zv = (float)Tz[row * 72 + k];
            float a = fmaxf(fmaf(zv, s_, h_), 0.f);
            accL[r][0] = fmaf(a, w2.x, accL[r][0]);
            accL[r][1] = fmaf(a, w2.y, accL[r][1]);
            accL[r][2] = fmaf(a, w2.z, accL[r][2]);
            accL[r][3] = fmaf(a, w2.w, accL[r][3]);
        }
    }
    #pragma unroll
    for (int r = 0; r < 2; ++r) {
        int row = base + ty + 64 * r;
        if (row < n) {
            float4 v;
            v.x = accL[r][0]; v.y = accL[r][1]; v.z = accL[r][2]; v.w = accL[r][3];
            *(float4*)(out + (size_t)row * 32 + 4 * tx) = v;
        }
    }
}

// ---------------- final linear (FALLBACK path) --------------------------------
__global__ __launch_bounds__(256) void gin_lin(const unsigned short* __restrict__ zin,
                                               const float* __restrict__ stats,
                                               const float* __restrict__ gammas,
                                               const float* __restrict__ betas,
                                               float fN,
                                               const float* __restrict__ lw,
                                               const float* __restrict__ lb,
                                               float* __restrict__ out, int n) {
    __shared__ float Z[128 * 68];
    int tid = threadIdx.x;
    int base = blockIdx.x * 128;
    int cq = (tid & 15) * 4;
    float4 sc4, sh4;
    {
        float t0[4], t1[4];
        #pragma unroll
        for (int j = 0; j < 4; ++j) {
            int f = cq + j;
            float mu  = stats[256 + f] / fN;
            float var = stats[256 + 64 + f] / fN - mu * mu;
            float g   = gammas[128 + f];
            float grs = g * rsqrtf(var + 1e-5f);
            t0[j] = grs;
            t1[j] = betas[128 + f] - grs * mu;
        }
        sc4 = make_float4(t0[0], t0[1], t0[2], t0[3]);
        sh4 = make_float4(t1[0], t1[1], t1[2], t1[3]);
    }
    {
        const ushort4* __restrict__ src = (const ushort4*)(zin + (size_t)base * 64);
        #pragma unroll
        for (int it = 0; it < 8; ++it) {
            int idx4 = it * 256 + tid;
            int row = idx4 >> 4, c = (idx4 & 15) * 4;
            float4 v = make_float4(0.f, 0.f, 0.f, 0.f);
            if (base + row < n) {
                ushort4 u = src[idx4];
                float2 f0 = __half22float2(*(const __half2*)&u.x);
                float2 f1 = __half22float2(*(const __half2*)&u.z);
                v = make_float4(f0.x, f0.y, f1.x, f1.y);
            }
            float4 r;
            r.x = fmaxf(fmaf(v.x, sc4.x, sh4.x), 0.f);
            r.y = fmaxf(fmaf(v.y, sc4.y, sh4.y), 0.f);
            r.z = fmaxf(fmaf(v.z, sc4.z, sh4.z), 0.f);
            r.w = fmaxf(fmaf(v.w, sc4.w, sh4.w), 0.f);
            *(float4*)&Z[row * 68 + c] = r;
        }
    }
    __syncthreads();
    int tx = tid & 7, ty = tid >> 3;  // 8 x 32
    float acc[4][4];
    {
        float4 b = *(const float4*)(lb + 4 * tx);
        #pragma unroll
        for (int r = 0; r < 4; ++r) {
            acc[r][0] = b.x; acc[r][1] = b.y; acc[r][2] = b.z; acc[r][3] = b.w;
        }
    }
    #pragma unroll 4
    for (int k = 0; k < 64; ++k) {
        float4 w = *(const float4*)(lw + k * 32 + 4 * tx);
        #pragma unroll
        for (int r = 0; r < 4; ++r) {
            float a = Z[(ty + 32 * r) * 68 + k];
            acc[r][0] = fmaf(a, w.x, acc[r][0]);
            acc[r][1] = fmaf(a, w.y, acc[r][1]);
            acc[r][2] = fmaf(a, w.z, acc[r][2]);
            acc[r][3] = fmaf(a, w.w, acc[r][3]);
        }
    }
    #pragma unroll
    for (int r = 0; r < 4; ++r) {
        int row = base + ty + 32 * r;
        if (row < n) {
            float4 v;
            v.x = acc[r][0]; v.y = acc[r][1]; v.z = acc[r][2]; v.w = acc[r][3];
            *(float4*)(out + (size_t)row * 32 + 4 * tx) = v;
        }
    }
}

extern "C" void kernel_launch(void* const* d_in, const int* in_sizes, int n_in,
                              void* d_out, int out_size, void* d_ws, size_t ws_size,
                              hipStream_t stream) {
    const float* x      = (const float*)d_in[0];
    const void*  edge   = d_in[1];
    const float* W1s    = (const float*)d_in[2];
    const float* b1s    = (const float*)d_in[3];
    const float* W2s    = (const float*)d_in[4];
    const float* b2s    = (const float*)d_in[5];
    const float* gammas = (const float*)d_in[6];
    const float* betas  = (const float*)d_in[7];
    const float* epss   = (const float*)d_in[8];
    const float* lin_w  = (const float*)d_in[9];
    const float* lin_b  = (const float*)d_in[10];
    float* out = (float*)d_out;

    const int N = in_sizes[0] / 64;
    const int E = in_sizes[1] / 2;
    const int NB = (N + 511) >> 9;  // coarse buckets
    const float fN = (float)N;

    char* w = (char*)d_ws;
    auto take = [&](size_t bytes) {
        char* p = w;
        w += (bytes + 255) & ~(size_t)255;
        return p;
    };
    unsigned short* x16 = (unsigned short*)take((size_t)N * 64 * 2);
    unsigned short* hA  = (unsigned short*)take((size_t)N * 64 * 2);
    unsigned short* hB  = (unsigned short*)take((size_t)N * 64 * 2);
    uint2* ebuf    = (uint2*)take((size_t)NB * BCAP * 8);
    int*   col     = (int*)take((size_t)NB * BCAP * 4);
    int*   rowbeg  = (int*)take((size_t)N * 4);
    int*   rowend  = (int*)take((size_t)N * 4);
    int*   gcount  = (int*)take((size_t)NBMAX * 4);   // 1024 B
    float* stats   = (float*)take(3 * 128 * 4);       // 1536 B, contiguous
    int*   bar     = (int*)take(256);                 // barrier counter, contiguous

    // zero gcount + stats + bar in one capture-safe memset
    hipMemsetAsync(gcount, 0, 1024 + 1536 + 256, stream);

    const int n16 = N * 16;
    const int nbin = (E + CHB - 1) / CHB;
    const int gx = (n16 + 255) / 256;
    gin_prep<<<nbin + gx, 256, 0, stream>>>(x, x16, n16, edge, gcount, ebuf, E, NB, nbin);
    gin_build<<<NB, 256, 0, stream>>>(ebuf, gcount, rowbeg, rowend, col, N);

    const int gMlp = (N + 127) / 128;

    // persistent megakernel only if ALL blocks are simultaneously resident
    bool mega = false;
    {
        int dev = 0;
        hipGetDevice(&dev);
        int numCU = 0;
        hipDeviceGetAttribute(&numCU, hipDeviceAttributeMultiprocessorCount, dev);
        int maxB = 0;
        hipOccupancyMaxActiveBlocksPerMultiprocessor(&maxB, gin_mega, 512, 0);
        if (maxB > 0 && numCU > 0 && (long long)maxB * numCU >= (long long)gMlp)
            mega = true;
    }
    if (mega) {
        gin_mega<<<gMlp, 512, 0, stream>>>(x16, hA, hB, rowbeg, rowend, col, epss,
                                           gammas, betas, fN, W1s, b1s, W2s, b2s,
                                           stats, N, lin_w, lin_b, out, bar, gMlp);
    } else {
        gin_fused<false><<<gMlp, 512, 0, stream>>>(x16, rowbeg, rowend, col, epss,
                                                   gammas, betas, fN, hA,
                                                   W1s, b1s, W2s, b2s, stats, 0, N);
        gin_fused<true><<<gMlp, 512, 0, stream>>>(hA, rowbeg, rowend, col, epss,
                                                  gammas, betas, fN, hB,
                                                  W1s, b1s, W2s, b2s, stats, 1, N);
        gin_fused<true><<<gMlp, 512, 0, stream>>>(hB, rowbeg, rowend, col, epss,
                                                  gammas, betas, fN, hA,
                                                  W1s, b1s, W2s, b2s, stats, 2, N);
        gin_lin<<<gMlp, 256, 0, stream>>>(hA, stats, gammas, betas, fN, lin_w, lin_b, out, N);
    }
}

// Round 9
// 303.371 us; speedup vs baseline: 1.0020x; 1.0020x over previous
//
#include <hip/hip_runtime.h>
#include <hip/hip_fp16.h>

#define NBMAX 256   // coarse buckets (N/512), must be <= 256
#define BCAP  8192  // fixed edge capacity per bucket (mean 6144, +26 sigma)
#define CHB   3584  // edges per binning block (335 blocks -> fills 256 CUs)

typedef _Float16 half8 __attribute__((ext_vector_type(8)));
typedef float f32x4 __attribute__((ext_vector_type(4)));

__device__ __forceinline__ unsigned short f2h(float f) {
    __half h = __float2half_rn(f);
    return *(unsigned short*)&h;
}

// exclusive scan of v over 256 threads (4 waves); all threads must call
__device__ __forceinline__ int scan256(int v, int* wsum, int* woff) {
    int t = threadIdx.x, lane = t & 63, wv = t >> 6;
    int x = v;
    #pragma unroll
    for (int d = 1; d < 64; d <<= 1) {
        int y = __shfl_up(x, d, 64);
        if (lane >= d) x += y;
    }
    if (lane == 63) wsum[wv] = x;
    __syncthreads();
    if (t == 0) {
        int a = 0;
        #pragma unroll
        for (int i = 0; i < 4; ++i) { woff[i] = a; a += wsum[i]; }
    }
    __syncthreads();
    return x - v + woff[wv];
}

// ---------------- combined prep: binscatter (blocks < nbin) ∥ x->fp16 ---------
__global__ __launch_bounds__(256) void gin_prep(const float* __restrict__ x,
                                                unsigned short* __restrict__ o, int n16,
                                                const void* __restrict__ edge,
                                                int* __restrict__ gcount,
                                                uint2* __restrict__ ebuf,
                                                int E, int nb, int nbin) {
    if ((int)blockIdx.x >= nbin) {
        // ---- x16 role ----
        int i = (blockIdx.x - nbin) * 256 + threadIdx.x;  // one float4 group
        if (i >= n16) return;
        float4 v = ((const float4*)x)[i];
        ushort4 u;
        u.x = f2h(v.x); u.y = f2h(v.y); u.z = f2h(v.z); u.w = f2h(v.w);
        ((ushort4*)o)[i] = u;
        return;
    }
    // ---- binscatter role ----
    __shared__ int cnt[NBMAX];
    __shared__ int dlt[NBMAX];
    __shared__ int cur[NBMAX];
    __shared__ int wsum[4], woff[4];
    __shared__ int s_is64;
    __shared__ uint2 buf[CHB];
    int t = threadIdx.x;
    int beg = blockIdx.x * CHB;
    int m = E - beg; if (m > CHB) m = CHB;
    if (t < nb) cnt[t] = 0;
    if (t == 0) s_is64 = 1;
    __syncthreads();
    {   // dtype detect: int64 edges have zero high words (ids << 2^32)
        int m2 = (E < 64) ? E : 64;
        if (t < m2 && ((const int*)edge)[2 * t + 1] != 0) s_is64 = 0;  // benign race
    }
    __syncthreads();
    int is64 = s_is64;
    for (int j = t; j < m; j += 256) {
        int e = beg + j;
        int d = is64 ? (int)((const long long*)edge)[E + e] : ((const int*)edge)[E + e];
        atomicAdd(&cnt[d >> 9], 1);
    }
    __syncthreads();
    int v = (t < nb) ? cnt[t] : 0;
    int excl = scan256(v, wsum, woff);
    if (t < nb) {
        int gb = v ? atomicAdd(&gcount[t], v) : 0;
        dlt[t] = t * BCAP + gb - excl;
        cur[t] = excl;
    }
    __syncthreads();
    for (int j = t; j < m; j += 256) {
        int e = beg + j;
        int s, d;
        if (is64) {
            s = (int)((const long long*)edge)[e];
            d = (int)((const long long*)edge)[E + e];
        } else {
            s = ((const int*)edge)[e];
            d = ((const int*)edge)[E + e];
        }
        int p = atomicAdd(&cur[d >> 9], 1);
        buf[p] = make_uint2((unsigned)s, (unsigned)d);
    }
    __syncthreads();
    for (int j = t; j < m; j += 256) {
        uint2 ed = buf[j];
        ebuf[j + dlt[(int)(ed.y >> 9)]] = ed;  // contiguous runs per bucket
    }
}

// ---------------- per-bucket CSR build (512 nodes/block) ----------------
__global__ __launch_bounds__(256) void gin_build(const uint2* __restrict__ ebuf,
                                                 const int* __restrict__ gcount,
                                                 int* __restrict__ rowbeg,
                                                 int* __restrict__ rowend,
                                                 int* __restrict__ col, int n) {
    __shared__ int cnt[512];
    __shared__ int off[512];
    __shared__ int wsum[4], woff[4];
    int b = blockIdx.x, t = threadIdx.x;
    int beg = b * BCAP;
    int end = beg + gcount[b];
    cnt[t] = 0; cnt[t + 256] = 0;
    __syncthreads();
    for (int j = beg + t; j < end; j += 256)
        atomicAdd(&cnt[(int)(ebuf[j].y & 511)], 1);
    __syncthreads();
    int v0 = cnt[2 * t], v1 = cnt[2 * t + 1];
    int ep = scan256(v0 + v1, wsum, woff);
    off[2 * t] = ep;
    off[2 * t + 1] = ep + v0;
    __syncthreads();
    int node0 = b * 512 + 2 * t;
    if (node0 < n) {
        rowbeg[node0] = beg + off[2 * t];
        rowend[node0] = beg + off[2 * t] + v0;
    }
    if (node0 + 1 < n) {
        rowbeg[node0 + 1] = beg + off[2 * t + 1];
        rowend[node0 + 1] = beg + off[2 * t + 1] + v1;
    }
    __syncthreads();
    for (int j = beg + t; j < end; j += 256) {
        uint2 ed = ebuf[j];
        int p = atomicAdd(&off[(int)(ed.y & 511)], 1);
        col[beg + p] = (int)ed.x;
    }
}

// ---------------- gather core (fp16 rows, 4 nodes per wave) ----------
template <bool APPLY>
__device__ __forceinline__ void accum8(float* acc, uint4 u,
                                       const float* sc, const float* sh) {
    float v[8];
    float2 f;
    f = __half22float2(*(const __half2*)&u.x); v[0] = f.x; v[1] = f.y;
    f = __half22float2(*(const __half2*)&u.y); v[2] = f.x; v[3] = f.y;
    f = __half22float2(*(const __half2*)&u.z); v[4] = f.x; v[5] = f.y;
    f = __half22float2(*(const __half2*)&u.w); v[6] = f.x; v[7] = f.y;
    #pragma unroll
    for (int j = 0; j < 8; ++j)
        acc[j] += APPLY ? fmaxf(fmaf(v[j], sc[j], sh[j]), 0.f) : v[j];
}

// writes the node's 64-feature t-row (fp16) to trow (LDS), stride-free.
// ci0 = prefetched col indices for the FIRST 16-edge chunk (issued a pass ago)
template <bool APPLY>
__device__ __forceinline__ void gather_node(const unsigned short* __restrict__ zb,
                                            int r0, int r1, int ci0,
                                            const int* __restrict__ col,
                                            float e1,
                                            const float* sc, const float* sh,
                                            _Float16* __restrict__ trow,
                                            int wid, int qn, int l16) {
    int r = l16 >> 3, c = l16 & 7;  // row parity / feature chunk (8 features)
    // self row (only r==0 lanes consume; issued early so it's in flight)
    uint4 su = make_uint4(0, 0, 0, 0);
    if (r == 0) su = *(const uint4*)(zb + (size_t)wid * 64 + 8 * c);

    float acc[8] = {0.f, 0.f, 0.f, 0.f, 0.f, 0.f, 0.f, 0.f};
    int ci = ci0;
    for (int b2 = r0; b2 < r1; b2 += 16) {
        if (b2 > r0) {  // chunk 0 uses the prefetched ci0
            int ce = b2 + l16;
            ci = col[ce < r1 ? ce : r1 - 1];  // 1 load -> 16 neighbor indices
        }
        uint4 u[8];
        bool p[8];
        #pragma unroll
        for (int s = 0; s < 8; ++s) {
            int j = 2 * s + r;
            p[s] = (b2 + j) < r1;
            int idx = __shfl(ci, 16 * qn + j);
            if (p[s]) u[s] = *(const uint4*)(zb + (size_t)idx * 64 + 8 * c);
        }
        #pragma unroll
        for (int s = 0; s < 8; ++s)
            if (p[s]) accum8<APPLY>(acc, u[s], sc, sh);
    }
    // reduce the 2 row parities — xor 8 stays inside this 16-lane quarter
    #pragma unroll
    for (int j = 0; j < 8; ++j)
        acc[j] += __shfl_xor(acc[j], 8);
    if (r == 0) {
        float s[8];
        float2 f;
        f = __half22float2(*(const __half2*)&su.x); s[0] = f.x; s[1] = f.y;
        f = __half22float2(*(const __half2*)&su.y); s[2] = f.x; s[3] = f.y;
        f = __half22float2(*(const __half2*)&su.z); s[4] = f.x; s[5] = f.y;
        f = __half22float2(*(const __half2*)&su.w); s[6] = f.x; s[7] = f.y;
        #pragma unroll
        for (int j = 0; j < 8; ++j) {
            float v = APPLY ? fmaxf(fmaf(s[j], sc[j], sh[j]), 0.f) : s[j];
            acc[j] = fmaf(e1, v, acc[j]);
        }
        uint4 o;
        o.x = (unsigned)f2h(acc[0]) | ((unsigned)f2h(acc[1]) << 16);
        o.y = (unsigned)f2h(acc[2]) | ((unsigned)f2h(acc[3]) << 16);
        o.z = (unsigned)f2h(acc[4]) | ((unsigned)f2h(acc[5]) << 16);
        o.w = (unsigned)f2h(acc[6]) | ((unsigned)f2h(acc[7]) << 16);
        *(uint4*)(trow + 8 * c) = o;
    }
}

// ---------------- one GIN layer for a 128-node block (shared by fused/mega) ---
// caller must have staged Wt (both mms), zeroed sS/sQ, computed sBN (if APPLY),
// and issued a __syncthreads(). Ends with stats flushed (block-synced).
template <bool APPLY>
__device__ __forceinline__ void gin_layer(const unsigned short* __restrict__ zb,
                                          const int* __restrict__ rowbeg,
                                          const int* __restrict__ rowend,
                                          const int* __restrict__ col,
                                          float e1,
                                          const float* __restrict__ b1,
                                          const float* __restrict__ b2,
                                          float* __restrict__ statsL,
                                          _Float16* __restrict__ Wt,
                                          _Float16* __restrict__ Tz,
                                          float* __restrict__ sS,
                                          float* __restrict__ sQ,
                                          const float* __restrict__ sBN,
                                          int base, int n) {
    int tid = threadIdx.x;
    int lane = tid & 63, wv = tid >> 6;   // wv 0..7
    int qn = lane >> 4;
    int l16 = lane & 15;
    int c8 = l16 & 7;
    float sc[8] = {1.f, 1.f, 1.f, 1.f, 1.f, 1.f, 1.f, 1.f};
    float sh[8] = {0.f, 0.f, 0.f, 0.f, 0.f, 0.f, 0.f, 0.f};
    if (APPLY) {
        *(float4*)&sc[0] = *(const float4*)&sBN[8 * c8];
        *(float4*)&sc[4] = *(const float4*)&sBN[8 * c8 + 4];
        *(float4*)&sh[0] = *(const float4*)&sBN[64 + 8 * c8];
        *(float4*)&sh[4] = *(const float4*)&sBN[64 + 8 * c8 + 4];
    }

    // ---- phase 1: gather 128 t-rows into Tz (4 passes of 32 nodes) ----
    int wvq = wv * 4 + qn;   // 0..31
    int cr0, cr1, pr0, pr1;
    {   // extents for pass 0 and 1
        int w0 = base + wvq;
        cr0 = 0; cr1 = 0;
        if (w0 < n) { cr0 = rowbeg[w0]; cr1 = rowend[w0]; }
        int w1 = w0 + 32;
        pr0 = 0; pr1 = 0;
        if (w1 < n) { pr0 = rowbeg[w1]; pr1 = rowend[w1]; }
    }
    int cci = 0;
    if (cr1 > cr0) { int ce = cr0 + l16; cci = col[ce < cr1 ? ce : cr1 - 1]; }
    #pragma unroll 1
    for (int p = 0; p < 4; ++p) {
        int nci = 0;
        if (pr1 > pr0) { int ce = pr0 + l16; nci = col[ce < pr1 ? ce : pr1 - 1]; }
        int fr0 = 0, fr1 = 0;
        {
            int w2 = base + (p + 2) * 32 + wvq;
            if (p < 2 && w2 < n) { fr0 = rowbeg[w2]; fr1 = rowend[w2]; }
        }
        int widl = p * 32 + wvq;
        int wid = base + widl;
        if (wid < n) {
            gather_node<APPLY>(zb, cr0, cr1, cci, col, e1, sc, sh,
                               Tz + widl * 72, wid, qn, l16);
        } else if (l16 < 8) {
            *(uint4*)(Tz + widl * 72 + 8 * c8) = make_uint4(0u, 0u, 0u, 0u);
        }
        cr0 = pr0; cr1 = pr1; cci = nci;
        pr0 = fr0; pr1 = fr1;
    }
    __syncthreads();

    // ---- phase 2: MFMA MLP, one 16-row tile per wave ----
    int g = qn, q = l16;
    int n0 = 16 * wv + q;        // node row (block-local)

    half8 tb0 = *(const half8*)&Tz[n0 * 72 + 8 * g];
    half8 tb1 = *(const half8*)&Tz[n0 * 72 + 32 + 8 * g];

    f32x4 acc[4];
    #pragma unroll
    for (int ft = 0; ft < 4; ++ft)
        acc[ft] = (f32x4){0.f, 0.f, 0.f, 0.f};

    // ---- mm1 ----
    #pragma unroll
    for (int ft = 0; ft < 4; ++ft) {
        half8 a0 = *(const half8*)&Wt[(16 * ft + q) * 72 + 8 * g];
        half8 a1 = *(const half8*)&Wt[(16 * ft + q) * 72 + 32 + 8 * g];
        acc[ft] = __builtin_amdgcn_mfma_f32_16x16x32_f16(a0, tb0, acc[ft], 0, 0, 0);
        acc[ft] = __builtin_amdgcn_mfma_f32_16x16x32_f16(a1, tb1, acc[ft], 0, 0, 0);
    }

    // ---- epilogue 1: bias + relu -> Tz reused as Z1 (own rows, no barrier) ----
    #pragma unroll
    for (int ft = 0; ft < 4; ++ft) {
        float4 b = *(const float4*)(b1 + 16 * ft + 4 * g);
        float v0 = fmaxf(acc[ft][0] + b.x, 0.f);
        float v1 = fmaxf(acc[ft][1] + b.y, 0.f);
        float v2 = fmaxf(acc[ft][2] + b.z, 0.f);
        float v3 = fmaxf(acc[ft][3] + b.w, 0.f);
        uint2 pk;
        pk.x = (unsigned)f2h(v0) | ((unsigned)f2h(v1) << 16);
        pk.y = (unsigned)f2h(v2) | ((unsigned)f2h(v3) << 16);
        *(uint2*)&Tz[n0 * 72 + 16 * ft + 4 * g] = pk;
    }

    // ---- mm2 (reads back own rows; lockstep intra-wave ordering) ----
    half8 zb0 = *(const half8*)&Tz[n0 * 72 + 8 * g];
    half8 zb1 = *(const half8*)&Tz[n0 * 72 + 32 + 8 * g];
    #pragma unroll
    for (int ft = 0; ft < 4; ++ft)
        acc[ft] = (f32x4){0.f, 0.f, 0.f, 0.f};
    #pragma unroll
    for (int ft = 0; ft < 4; ++ft) {
        half8 a0 = *(const half8*)&Wt[4608 + (16 * ft + q) * 72 + 8 * g];
        half8 a1 = *(const half8*)&Wt[4608 + (16 * ft + q) * 72 + 32 + 8 * g];
        acc[ft] = __builtin_amdgcn_mfma_f32_16x16x32_f16(a0, zb0, acc[ft], 0, 0, 0);
        acc[ft] = __builtin_amdgcn_mfma_f32_16x16x32_f16(a1, zb1, acc[ft], 0, 0, 0);
    }

    // ---- epilogue 2: bias + relu, BN stats, pack into Tz (own rows) ----
    int nodeg = base + n0;
    #pragma unroll
    for (int ft = 0; ft < 4; ++ft) {
        float4 b = *(const float4*)(b2 + 16 * ft + 4 * g);
        float v0 = fmaxf(acc[ft][0] + b.x, 0.f);
        float v1 = fmaxf(acc[ft][1] + b.y, 0.f);
        float v2 = fmaxf(acc[ft][2] + b.z, 0.f);
        float v3 = fmaxf(acc[ft][3] + b.w, 0.f);
        float s[4], sq[4];
        bool ok = nodeg < n;
        s[0] = ok ? v0 : 0.f; sq[0] = ok ? v0 * v0 : 0.f;
        s[1] = ok ? v1 : 0.f; sq[1] = ok ? v1 * v1 : 0.f;
        s[2] = ok ? v2 : 0.f; sq[2] = ok ? v2 * v2 : 0.f;
        s[3] = ok ? v3 : 0.f; sq[3] = ok ? v3 * v3 : 0.f;
        uint2 pk;
        pk.x = (unsigned)f2h(v0) | ((unsigned)f2h(v1) << 16);
        pk.y = (unsigned)f2h(v2) | ((unsigned)f2h(v3) << 16);
        *(uint2*)&Tz[n0 * 72 + 16 * ft + 4 * g] = pk;
        #pragma unroll
        for (int off = 1; off < 16; off <<= 1) {
            #pragma unroll
            for (int r2 = 0; r2 < 4; ++r2) {
                s[r2] += __shfl_xor(s[r2], off);
                sq[r2] += __shfl_xor(sq[r2], off);
            }
        }
        if (q == 0) {
            #pragma unroll
            for (int r2 = 0; r2 < 4; ++r2) {
                atomicAdd(&sS[16 * ft + 4 * g + r2], s[r2]);
                atomicAdd(&sQ[16 * ft + 4 * g + r2], sq[r2]);
            }
        }
    }
    __syncthreads();
    if (tid < 64) {
        atomicAdd(&statsL[tid], sS[tid]);
        atomicAdd(&statsL[64 + tid], sQ[tid]);
    }
}

// coalesced z16 copy-out: wave writes its own 16 rows (2 KB)
__device__ __forceinline__ void copyout_z16(const _Float16* __restrict__ Tz,
                                            unsigned short* __restrict__ z16,
                                            int base, int n) {
    int lane = threadIdx.x & 63, wv = threadIdx.x >> 6;
    #pragma unroll
    for (int t2 = 0; t2 < 2; ++t2) {
        int u = lane + 64 * t2;              // uint4 index within wave region
        int rloc = 16 * wv + (u >> 3);
        int node = base + rloc;
        if (node < n) {
            uint4 v = *(const uint4*)&Tz[rloc * 72 + (u & 7) * 8];
            *(uint4*)(z16 + (size_t)node * 64 + (u & 7) * 8) = v;
        }
    }
}

// ---------------- fallback per-layer kernel (round-6 proven) ------------------
template <bool APPLY>
__global__ __launch_bounds__(512, 4) void gin_fused(const unsigned short* __restrict__ zb,
                                                    const int* __restrict__ rowbeg,
                                                    const int* __restrict__ rowend,
                                                    const int* __restrict__ col,
                                                    const float* __restrict__ epss,
                                                    const float* __restrict__ gammas,
                                                    const float* __restrict__ betas,
                                                    float fN,
                                                    unsigned short* __restrict__ z16,
                                                    const float* __restrict__ W1g,
                                                    const float* __restrict__ b1g,
                                                    const float* __restrict__ W2g,
                                                    const float* __restrict__ b2g,
                                                    float* __restrict__ stats,
                                                    int layer, int n) {
    __shared__ _Float16 Wt[2 * 64 * 72];
    __shared__ _Float16 Tz[128 * 72];
    __shared__ float sS[64], sQ[64];
    __shared__ float sBN[128];
    int tid = threadIdx.x;
    int base = blockIdx.x * 128;
    const float* __restrict__ W1 = W1g + layer * 4096;
    const float* __restrict__ W2 = W2g + layer * 4096;
    for (int i = tid; i < 4096; i += 512) {
        int k = i >> 6, nn = i & 63;
        Wt[nn * 72 + k]        = (_Float16)W1[i];
        Wt[4608 + nn * 72 + k] = (_Float16)W2[i];
    }
    if (tid < 64) {
        sS[tid] = 0.f; sQ[tid] = 0.f;
        if (APPLY) {
            float mu  = stats[(layer - 1) * 128 + tid] / fN;
            float var = stats[(layer - 1) * 128 + 64 + tid] / fN - mu * mu;
            float g   = gammas[(layer - 1) * 64 + tid];
            float grs = g * rsqrtf(var + 1e-5f);
            sBN[tid]      = grs;
            sBN[64 + tid] = betas[(layer - 1) * 64 + tid] - grs * mu;
        }
    }
    __syncthreads();
    gin_layer<APPLY>(zb, rowbeg, rowend, col, 1.f + epss[layer],
                     b1g + layer * 64, b2g + layer * 64, stats + layer * 128,
                     Wt, Tz, sS, sQ, sBN, base, n);
    copyout_z16(Tz, z16, base, n);
}

// ---------------- device-wide barrier (all blocks resident, gated on host) ----
__device__ __forceinline__ void megabar(int* __restrict__ bar, int target) {
    __syncthreads();
    if (threadIdx.x == 0) {
        __threadfence();   // release: drain + L2 writeback (device scope)
        __hip_atomic_fetch_add(bar, 1, __ATOMIC_RELEASE, __HIP_MEMORY_SCOPE_AGENT);
        while (__hip_atomic_load(bar, __ATOMIC_ACQUIRE, __HIP_MEMORY_SCOPE_AGENT) < target)
            __builtin_amdgcn_s_sleep(16);
    }
    __syncthreads();
    __threadfence();       // acquire: invalidate local caches before cross-XCD reads
}

// ---------------- persistent megakernel: 3 layers + final linear --------------
// Launched only when all blocks are co-resident (host occupancy gate).
// launch_bounds(512,4): 128-VGPR cap (actual ~60, like gin_fused) — round-8's
// (512,8) forced VGPR=32 and spilled ~1.4GB to scratch. LDS (37.9KB -> 4
// blocks/CU -> 1024 slots) is the residency limit; at 60 VGPR those 4 blocks
// (32 waves/CU) still fit the register file, so the occupancy gate still passes.
__global__ __launch_bounds__(512, 4) void gin_mega(const unsigned short* __restrict__ x16,
                                                   unsigned short* __restrict__ hA,
                                                   unsigned short* __restrict__ hB,
                                                   const int* __restrict__ rowbeg,
                                                   const int* __restrict__ rowend,
                                                   const int* __restrict__ col,
                                                   const float* __restrict__ epss,
                                                   const float* __restrict__ gammas,
                                                   const float* __restrict__ betas,
                                                   float fN,
                                                   const float* __restrict__ W1g,
                                                   const float* __restrict__ b1g,
                                                   const float* __restrict__ W2g,
                                                   const float* __restrict__ b2g,
                                                   float* __restrict__ stats, int n,
                                                   const float* __restrict__ lw,
                                                   const float* __restrict__ lb,
                                                   float* __restrict__ out,
                                                   int* __restrict__ bar, int nblocks) {
    __shared__ _Float16 Wt[2 * 64 * 72];
    __shared__ _Float16 Tz[128 * 72];
    __shared__ float sS[64], sQ[64];
    __shared__ float sBN[128];
    int tid = threadIdx.x;
    int base = blockIdx.x * 128;

    #pragma unroll 1
    for (int L = 0; L < 3; ++L) {
        const unsigned short* zb = (L == 0) ? x16 : ((L == 1) ? hA : hB);
        const float* W1 = W1g + L * 4096;
        const float* W2 = W2g + L * 4096;
        for (int i = tid; i < 4096; i += 512) {
            int k = i >> 6, nn = i & 63;
            Wt[nn * 72 + k]        = (_Float16)W1[i];
            Wt[4608 + nn * 72 + k] = (_Float16)W2[i];
        }
        if (tid < 64) {
            sS[tid] = 0.f; sQ[tid] = 0.f;
            if (L > 0) {   // stats[L-1] fresh: read after previous megabar
                float mu  = stats[(L - 1) * 128 + tid] / fN;
                float var = stats[(L - 1) * 128 + 64 + tid] / fN - mu * mu;
                float g   = gammas[(L - 1) * 64 + tid];
                float grs = g * rsqrtf(var + 1e-5f);
                sBN[tid]      = grs;
                sBN[64 + tid] = betas[(L - 1) * 64 + tid] - grs * mu;
            }
        }
        __syncthreads();
        float e1 = 1.f + epss[L];
        if (L > 0)
            gin_layer<true>(zb, rowbeg, rowend, col, e1, b1g + L * 64, b2g + L * 64,
                            stats + L * 128, Wt, Tz, sS, sQ, sBN, base, n);
        else
            gin_layer<false>(zb, rowbeg, rowend, col, e1, b1g, b2g,
                             stats, Wt, Tz, sS, sQ, sBN, base, n);
        if (L < 2) copyout_z16(Tz, (L == 0) ? hA : hB, base, n);
        megabar(bar, nblocks * (L + 1));
    }

    // ---- final linear from resident Tz (layer-2 rows), BN folded ----
    float* Wl = (float*)Wt;                   // Wt dead -> 8 KB fp32 [64][32]
    for (int i = tid; i < 2048; i += 512) Wl[i] = lw[i];
    if (tid < 64) {
        float mu  = stats[256 + tid] / fN;
        float var = stats[256 + 64 + tid] / fN - mu * mu;
        float g2  = gammas[128 + tid];
        float grs = g2 * rsqrtf(var + 1e-5f);
        sBN[tid]      = grs;
        sBN[64 + tid] = betas[128 + tid] - grs * mu;
    }
    __syncthreads();
    int tx = tid & 7, ty = tid >> 3;          // 8 x 64
    float accL[2][4];
    {
        float4 b = *(const float4*)(lb + 4 * tx);
        #pragma unroll
        for (int r = 0; r < 2; ++r) {
            accL[r][0] = b.x; accL[r][1] = b.y; accL[r][2] = b.z; accL[r][3] = b.w;
        }
    }
    #pragma unroll 4
    for (int k = 0; k < 64; ++k) {
        float4 w2 = *(const float4*)&Wl[k * 32 + 4 * tx];
        float s_ = sBN[k], h_ = sBN[64 + k];
        #pragma unroll
        for (int r = 0; r < 2; ++r) {
            int row = ty + 64 * r;
            float zv = (float)Tz[row * 72 + k];
            float a = fmaxf(fmaf(zv, s_, h_), 0.f);
            accL[r][0] = fmaf(a, w2.x, accL[r][0]);
            accL[r][1] = fmaf(a, w2.y, accL[r][1]);
            accL[r][2] = fmaf(a, w2.z, accL[r][2]);
            accL[r][3] = fmaf(a, w2.w, accL[r][3]);
        }
    }
    #pragma unroll
    for (int r = 0; r < 2; ++r) {
        int row = base + ty + 64 * r;
        if (row < n) {
            float4 v;
            v.x = accL[r][0]; v.y = accL[r][1]; v.z = accL[r][2]; v.w = accL[r][3];
            *(float4*)(out + (size_t)row * 32 + 4 * tx) = v;
        }
    }
}

// ---------------- final linear (FALLBACK path) --------------------------------
__global__ __launch_bounds__(256) void gin_lin(const unsigned short* __restrict__ zin,
                                               const float* __restrict__ stats,
                                               const float* __restrict__ gammas,
                                               const float* __restrict__ betas,
                                               float fN,
                                               const float* __restrict__ lw,
                                               const float* __restrict__ lb,
                                               float* __restrict__ out, int n) {
    __shared__ float Z[128 * 68];
    int tid = threadIdx.x;
    int base = blockIdx.x * 128;
    int cq = (tid & 15) * 4;
    float4 sc4, sh4;
    {
        float t0[4], t1[4];
        #pragma unroll
        for (int j = 0; j < 4; ++j) {
            int f = cq + j;
            float mu  = stats[256 + f] / fN;
            float var = stats[256 + 64 + f] / fN - mu * mu;
            float g   = gammas[128 + f];
            float grs = g * rsqrtf(var + 1e-5f);
            t0[j] = grs;
            t1[j] = betas[128 + f] - grs * mu;
        }
        sc4 = make_float4(t0[0], t0[1], t0[2], t0[3]);
        sh4 = make_float4(t1[0], t1[1], t1[2], t1[3]);
    }
    {
        const ushort4* __restrict__ src = (const ushort4*)(zin + (size_t)base * 64);
        #pragma unroll
        for (int it = 0; it < 8; ++it) {
            int idx4 = it * 256 + tid;
            int row = idx4 >> 4, c = (idx4 & 15) * 4;
            float4 v = make_float4(0.f, 0.f, 0.f, 0.f);
            if (base + row < n) {
                ushort4 u = src[idx4];
                float2 f0 = __half22float2(*(const __half2*)&u.x);
                float2 f1 = __half22float2(*(const __half2*)&u.z);
                v = make_float4(f0.x, f0.y, f1.x, f1.y);
            }
            float4 r;
            r.x = fmaxf(fmaf(v.x, sc4.x, sh4.x), 0.f);
            r.y = fmaxf(fmaf(v.y, sc4.y, sh4.y), 0.f);
            r.z = fmaxf(fmaf(v.z, sc4.z, sh4.z), 0.f);
            r.w = fmaxf(fmaf(v.w, sc4.w, sh4.w), 0.f);
            *(float4*)&Z[row * 68 + c] = r;
        }
    }
    __syncthreads();
    int tx = tid & 7, ty = tid >> 3;  // 8 x 32
    float acc[4][4];
    {
        float4 b = *(const float4*)(lb + 4 * tx);
        #pragma unroll
        for (int r = 0; r < 4; ++r) {
            acc[r][0] = b.x; acc[r][1] = b.y; acc[r][2] = b.z; acc[r][3] = b.w;
        }
    }
    #pragma unroll 4
    for (int k = 0; k < 64; ++k) {
        float4 w = *(const float4*)(lw + k * 32 + 4 * tx);
        #pragma unroll
        for (int r = 0; r < 4; ++r) {
            float a = Z[(ty + 32 * r) * 68 + k];
            acc[r][0] = fmaf(a, w.x, acc[r][0]);
            acc[r][1] = fmaf(a, w.y, acc[r][1]);
            acc[r][2] = fmaf(a, w.z, acc[r][2]);
            acc[r][3] = fmaf(a, w.w, acc[r][3]);
        }
    }
    #pragma unroll
    for (int r = 0; r < 4; ++r) {
        int row = base + ty + 32 * r;
        if (row < n) {
            float4 v;
            v.x = acc[r][0]; v.y = acc[r][1]; v.z = acc[r][2]; v.w = acc[r][3];
            *(float4*)(out + (size_t)row * 32 + 4 * tx) = v;
        }
    }
}

extern "C" void kernel_launch(void* const* d_in, const int* in_sizes, int n_in,
                              void* d_out, int out_size, void* d_ws, size_t ws_size,
                              hipStream_t stream) {
    const float* x      = (const float*)d_in[0];
    const void*  edge   = d_in[1];
    const float* W1s    = (const float*)d_in[2];
    const float* b1s    = (const float*)d_in[3];
    const float* W2s    = (const float*)d_in[4];
    const float* b2s    = (const float*)d_in[5];
    const float* gammas = (const float*)d_in[6];
    const float* betas  = (const float*)d_in[7];
    const float* epss   = (const float*)d_in[8];
    const float* lin_w  = (const float*)d_in[9];
    const float* lin_b  = (const float*)d_in[10];
    float* out = (float*)d_out;

    const int N = in_sizes[0] / 64;
    const int E = in_sizes[1] / 2;
    const int NB = (N + 511) >> 9;  // coarse buckets
    const float fN = (float)N;

    char* w = (char*)d_ws;
    auto take = [&](size_t bytes) {
        char* p = w;
        w += (bytes + 255) & ~(size_t)255;
        return p;
    };
    unsigned short* x16 = (unsigned short*)take((size_t)N * 64 * 2);
    unsigned short* hA  = (unsigned short*)take((size_t)N * 64 * 2);
    unsigned short* hB  = (unsigned short*)take((size_t)N * 64 * 2);
    uint2* ebuf    = (uint2*)take((size_t)NB * BCAP * 8);
    int*   col     = (int*)take((size_t)NB * BCAP * 4);
    int*   rowbeg  = (int*)take((size_t)N * 4);
    int*   rowend  = (int*)take((size_t)N * 4);
    int*   gcount  = (int*)take((size_t)NBMAX * 4);   // 1024 B
    float* stats   = (float*)take(3 * 128 * 4);       // 1536 B, contiguous
    int*   bar     = (int*)take(256);                 // barrier counter, contiguous

    // zero gcount + stats + bar in one capture-safe memset
    hipMemsetAsync(gcount, 0, 1024 + 1536 + 256, stream);

    const int n16 = N * 16;
    const int nbin = (E + CHB - 1) / CHB;
    const int gx = (n16 + 255) / 256;
    gin_prep<<<nbin + gx, 256, 0, stream>>>(x, x16, n16, edge, gcount, ebuf, E, NB, nbin);
    gin_build<<<NB, 256, 0, stream>>>(ebuf, gcount, rowbeg, rowend, col, N);

    const int gMlp = (N + 127) / 128;

    // persistent megakernel only if ALL blocks are simultaneously resident
    bool mega = false;
    {
        int dev = 0;
        hipGetDevice(&dev);
        int numCU = 0;
        hipDeviceGetAttribute(&numCU, hipDeviceAttributeMultiprocessorCount, dev);
        int maxB = 0;
        hipOccupancyMaxActiveBlocksPerMultiprocessor(&maxB, gin_mega, 512, 0);
        if (maxB > 0 && numCU > 0 && (long long)maxB * numCU >= (long long)gMlp)
            mega = true;
    }
    if (mega) {
        gin_mega<<<gMlp, 512, 0, stream>>>(x16, hA, hB, rowbeg, rowend, col, epss,
                                           gammas, betas, fN, W1s, b1s, W2s, b2s,
                                           stats, N, lin_w, lin_b, out, bar, gMlp);
    } else {
        gin_fused<false><<<gMlp, 512, 0, stream>>>(x16, rowbeg, rowend, col, epss,
                                                   gammas, betas, fN, hA,
                                                   W1s, b1s, W2s, b2s, stats, 0, N);
        gin_fused<true><<<gMlp, 512, 0, stream>>>(hA, rowbeg, rowend, col, epss,
                                                  gammas, betas, fN, hB,
                                                  W1s, b1s, W2s, b2s, stats, 1, N);
        gin_fused<true><<<gMlp, 512, 0, stream>>>(hB, rowbeg, rowend, col, epss,
                                                  gammas, betas, fN, hA,
                                                  W1s, b1s, W2s, b2s, stats, 2, N);
        gin_lin<<<gMlp, 256, 0, stream>>>(hA, stats, gammas, betas, fN, lin_w, lin_b, out, N);
    }
}